// Round 2
// baseline (280.272 us; speedup 1.0000x reference)
//
#include <hip/hip_runtime.h>
#include <cstdint>

// ---------------------------------------------------------------------------
// Round 15 vs round 14 (264 µs, regression) vs r13 (246 µs): r14 post-mortem
// showed swizzle works (conflicts 6.7M->0) but 64KB LDS + bounds(256,2) halved
// occupancy and exposed the per-K-step load latency (128^2 tile = only ~620cy
// MFMA/step). Fix: BIGGER TILE, same 2-phase. BM=128 x BN=256, BK=64, 512 thr
// (8 waves, 64x64 each): 2x MFMA per step (~1242 cy/CU) > L2 latency, LDS
// read-traffic per FLOP halves, LDS = 96KB dynamic (2-buf). BM stays 128 so
// expert boundaries (128-aligned) never cross a tile -> routing/assign/prep/
// workspace untouched. Swizzle kept (free, conflict-confound removed).
// Predicted: gemm1 66 -> ~20 µs, MfmaUtil ~35%, conflicts 0, total ~190.
// ---------------------------------------------------------------------------

#define T_TOK 4096
#define D_DIM 512
#define F_DIM 2048
#define E_EXP 8
#define NROWS 9216      // 8192 assignments + 8*128 pad
#define MAXTILES 72     // NROWS / 128

typedef __bf16 bf16x8 __attribute__((ext_vector_type(8)));
typedef float  f32x4  __attribute__((ext_vector_type(4)));
typedef unsigned short u16;

__device__ __forceinline__ u16 f2b(float f) {
    return __builtin_bit_cast(unsigned short, (__bf16)f);
}
__device__ __forceinline__ void gload16(void* lds, const void* g) {
    __builtin_amdgcn_global_load_lds(
        (const __attribute__((address_space(1))) void*)g,
        (__attribute__((address_space(3))) void*)lds, 16, 0, 0);
}
// tanh-approx GELU (err ~3e-4 << bf16 ulp)
__device__ __forceinline__ float gelu_f(float v) {
    float z = 0.7978845608f * (v + 0.044715f * v * v * v);
    float t = 1.0f - 2.0f / (1.0f + __expf(2.0f * z));
    return 0.5f * v * (1.0f + t);
}

// ---------------- init (zeroing) + anchors in ONE dispatch ------------------
__global__ void init_k(int* __restrict__ cnt, int* __restrict__ rowmap,
                       float* __restrict__ rowgate, float* __restrict__ outm,
                       const float* __restrict__ anchors,
                       float* __restrict__ an, float* __restrict__ dout_an) {
    int tid = blockIdx.x * 256 + threadIdx.x;
    int nth = gridDim.x * 256;
    if (tid < E_EXP) cnt[tid] = 0;
    for (int i = tid; i < NROWS; i += nth) { rowmap[i] = -1; rowgate[i] = 0.f; }
    float4* o4 = (float4*)outm;
    for (int i = tid; i < (T_TOK * D_DIM) / 4; i += nth)
        o4[i] = float4{0.f, 0.f, 0.f, 0.f};
    // last block: anchor norms, 32 threads per anchor (8 anchors x 32 = 256)
    if (blockIdx.x == gridDim.x - 1) {
        int t = threadIdx.x;
        int e = t >> 5, l = t & 31;
        const float4* ar = (const float4*)(anchors + e * D_DIM + l * 16);
        float4 v0 = ar[0], v1 = ar[1], v2 = ar[2], v3 = ar[3];
        float ss = v0.x*v0.x + v0.y*v0.y + v0.z*v0.z + v0.w*v0.w
                 + v1.x*v1.x + v1.y*v1.y + v1.z*v1.z + v1.w*v1.w
                 + v2.x*v2.x + v2.y*v2.y + v2.z*v2.z + v2.w*v2.w
                 + v3.x*v3.x + v3.y*v3.y + v3.z*v3.z + v3.w*v3.w;
#pragma unroll
        for (int off = 16; off >= 1; off >>= 1) ss += __shfl_xor(ss, off, 32);
        float inv = 1.0f / fmaxf(sqrtf(ss), 1e-8f);
        float o[16] = {v0.x*inv, v0.y*inv, v0.z*inv, v0.w*inv,
                       v1.x*inv, v1.y*inv, v1.z*inv, v1.w*inv,
                       v2.x*inv, v2.y*inv, v2.z*inv, v2.w*inv,
                       v3.x*inv, v3.y*inv, v3.z*inv, v3.w*inv};
#pragma unroll
        for (int i = 0; i < 16; ++i) {
            an[e * D_DIM + l * 16 + i] = o[i];
            dout_an[e * D_DIM + l * 16 + i] = o[i];
        }
    }
}

// ---------------- routing: 4 threads per token ------------------------------
__global__ void routing_k(const float* __restrict__ x, const float* __restrict__ an,
                          float* __restrict__ dout_scores, float* __restrict__ dout_idx,
                          int* __restrict__ idxs, float* __restrict__ gates,
                          int* __restrict__ cnt) {
    __shared__ float anl[E_EXP * 544];   // [e][p*136 + i], i<128
    __shared__ int hist[E_EXP];
    int tid = threadIdx.x;
    if (tid < E_EXP) hist[tid] = 0;
    for (int i = tid; i < E_EXP * D_DIM; i += 256) {
        int e = i >> 9, d = i & 511;
        anl[e * 544 + (d >> 7) * 136 + (d & 127)] = an[i];
    }
    __syncthreads();

    int p = tid & 3;
    int tok = blockIdx.x * 64 + (tid >> 2);
    const float4* xr = (const float4*)(x + (size_t)tok * D_DIM + p * 128);
    const float* ab = &anl[p * 136];
    float dot[E_EXP] = {};
    float ss = 0.f;
    for (int c = 0; c < 32; ++c) {
        float4 xv = xr[c];
        ss += xv.x*xv.x + xv.y*xv.y + xv.z*xv.z + xv.w*xv.w;
#pragma unroll
        for (int e = 0; e < E_EXP; ++e) {
            float4 av = *(const float4*)&ab[e * 544 + c * 4];
            dot[e] += xv.x*av.x + xv.y*av.y + xv.z*av.z + xv.w*av.w;
        }
    }
#pragma unroll
    for (int off = 1; off <= 2; off <<= 1) {
        ss += __shfl_xor(ss, off, 64);
#pragma unroll
        for (int e = 0; e < E_EXP; ++e) dot[e] += __shfl_xor(dot[e], off, 64);
    }

    if (p == 0) {
        float inv = 1.0f / fmaxf(sqrtf(ss), 1e-8f);
        float s[E_EXP];
#pragma unroll
        for (int e = 0; e < E_EXP; ++e) s[e] = dot[e] * inv;
        int i0 = 0; float b0 = s[0];
#pragma unroll
        for (int e = 1; e < E_EXP; ++e) if (s[e] > b0) { b0 = s[e]; i0 = e; }
        int i1 = -1; float b1v = -1e30f;
#pragma unroll
        for (int e = 0; e < E_EXP; ++e)
            if (e != i0 && s[e] > b1v) { b1v = s[e]; i1 = e; }
        if (i1 < 0) { i1 = (i0 + 1) & 7; b1v = s[i1]; }   // NaN-safety
        float g0 = 1.0f / (1.0f + expf(b1v - b0));
        float g1 = 1.0f - g0;
#pragma unroll
        for (int e = 0; e < E_EXP; ++e) dout_scores[tok * E_EXP + e] = s[e];
        dout_idx[tok * 2 + 0] = (float)i0;
        dout_idx[tok * 2 + 1] = (float)i1;
        idxs[tok * 2 + 0] = i0; idxs[tok * 2 + 1] = i1;
        gates[tok * 2 + 0] = g0; gates[tok * 2 + 1] = g1;
        atomicAdd(&hist[i0], 1);
        atomicAdd(&hist[i1], 1);
    }
    __syncthreads();
    if (tid < E_EXP) atomicAdd(&cnt[tid], hist[tid]);
}

// ---------------- offsets + slot assignment, ONE block (LDS cursors) --------
__global__ void assign_k(const int* __restrict__ cnt, int* __restrict__ offs,
                         const int* __restrict__ idxs, const float* __restrict__ gates,
                         int* __restrict__ rowmap, float* __restrict__ rowgate) {
    __shared__ int scur[E_EXP];
    int tid = threadIdx.x;
    if (tid == 0) {
        int acc = 0;
        for (int e = 0; e < E_EXP; ++e) {
            offs[e] = acc; scur[e] = acc;
            acc += (cnt[e] + 127) & ~127;
        }
        offs[E_EXP] = acc;
    }
    __syncthreads();
    for (int t = tid; t < T_TOK; t += 1024) {
#pragma unroll
        for (int k = 0; k < 2; ++k) {
            int e = idxs[t * 2 + k];
            e = min(max(e, 0), E_EXP - 1);
            int r = atomicAdd(&scur[e], 1);
            if (r >= 0 && r < NROWS) {
                rowmap[r] = t;
                rowgate[r] = gates[t * 2 + k];
            }
        }
    }
}

// ---------------- prep: gather + transpose(W1) + transpose(W2), ONE dispatch
__device__ __forceinline__ void tbody(const float* __restrict__ in,
                                      u16* __restrict__ out, int R, int C,
                                      int c0, int r0, int tid,
                                      float (*t)[65]) {
    int cq = tid & 15, rb = tid >> 4;
#pragma unroll
    for (int pass = 0; pass < 4; ++pass) {
        int rr = rb + pass * 16;
        float4 v = *(const float4*)(in + (size_t)(r0 + rr) * C + c0 + cq * 4);
        t[rr][cq * 4 + 0] = v.x; t[rr][cq * 4 + 1] = v.y;
        t[rr][cq * 4 + 2] = v.z; t[rr][cq * 4 + 3] = v.w;
    }
    __syncthreads();
    int rg = tid & 15, cb = tid >> 4;
#pragma unroll
    for (int pass = 0; pass < 4; ++pass) {
        int c = cb + pass * 16;
        ushort4 o;
        o.x = f2b(t[rg * 4 + 0][c]); o.y = f2b(t[rg * 4 + 1][c]);
        o.z = f2b(t[rg * 4 + 2][c]); o.w = f2b(t[rg * 4 + 3][c]);
        *(ushort4*)(out + (size_t)(c0 + c) * R + r0 + rg * 4) = o;
    }
}

#define T1_BASE NROWS                    // 9216
#define T2_BASE (NROWS + 2048)           // 11264
#define PREP_BLOCKS (NROWS + 4096)       // 13312

__global__ void prep_k(const float* __restrict__ x, const int* __restrict__ rowmap,
                       u16* __restrict__ Xg,
                       const float* __restrict__ W1, u16* __restrict__ W1T,
                       const float* __restrict__ W2, u16* __restrict__ W2T) {
    __shared__ float tsh[64][65];
    int b = blockIdx.x;
    int tid = threadIdx.x;
    if (b < T1_BASE) {                      // gather row b
        int t = rowmap[b];
        int c = tid * 2;
        ushort2 o;
        if (t < 0 || t >= T_TOK) { o.x = 0; o.y = 0; }
        else {
            float2 v = *(const float2*)(x + (size_t)t * D_DIM + c);
            o.x = f2b(v.x); o.y = f2b(v.y);
        }
        *(ushort2*)(Xg + (size_t)b * D_DIM + c) = o;
    } else if (b < T2_BASE) {               // W1 [E][512][2048] -> [E][2048][512]
        int tt = b - T1_BASE;
        int bx = tt & 31, by = (tt >> 5) & 7, bz = tt >> 8;
        size_t zoff = (size_t)bz * D_DIM * F_DIM;
        tbody(W1 + zoff, W1T + zoff, D_DIM, F_DIM, bx * 64, by * 64, tid, tsh);
    } else {                                // W2 [E][2048][512] -> [E][512][2048]
        int tt = b - T2_BASE;
        int bx = tt & 7, by = (tt >> 3) & 31, bz = tt >> 8;
        size_t zoff = (size_t)bz * D_DIM * F_DIM;
        tbody(W2 + zoff, W2T + zoff, F_DIM, D_DIM, bx * 64, by * 64, tid, tsh);
    }
}

// ---------------- grouped GEMM core (round 15: 128x256 tile, 8 waves) -------
// MODE 0: Hg = bf16(gelu(Xg @ W1e^T + b1e))         (N=F, K=D), nT=8
// MODE 1: out[tok] += gate*(Hg @ W2e^T + [z0]b2e)   (N=D, K=F, split-K=2), nT=2
// 1D grid; tile = (L%8)*(total/8) + L/8  -> contiguous m-tile range per XCD.
// 512 threads = 8 waves, wave grid 2m x 4n, 64x64 output per wave.
// LDS: dynamic 96 KB = 2 bufs x (A 128x64 + B 256x64) bf16, XOR col swizzle
// kc_eff = kc ^ (row&7); global source pre-swizzled (gload_lds dest linear).
// 2-phase: stage(next) -> compute(cur) -> vmcnt(0)+barrier. BM=128 keeps
// m-tiles expert-aligned (offs are 128-aligned) -> no routing changes.
#define ABUF (128 * 64)
#define BBUF (256 * 64)
template <int MODE>
__launch_bounds__(512, 2)
__global__ void gemm_k(const u16* __restrict__ A, int lda,
                       const u16* __restrict__ BtBase, int ldb,
                       u16* __restrict__ Hout, const float* __restrict__ b1,
                       float* __restrict__ outm, const float* __restrict__ b2,
                       const int* __restrict__ rowmap, const float* __restrict__ rowgate,
                       const int* __restrict__ offs, int kPer, int nT) {
    int L = blockIdx.x;
    int per = gridDim.x >> 3;
    int tile = (L & 7) * per + (L >> 3);
    int z = 0;
    if (MODE == 1) {                 // split-K 2: high half of tiles is z=1
        int half = gridDim.x >> 1;
        z = tile >= half; tile -= z * half;
    }
    int mtile = tile / nT;
    int n0 = (tile - mtile * nT) * 256;
    int row0 = mtile * 128;
    if (row0 >= offs[E_EXP]) return;
    int e = 0;
#pragma unroll
    for (int i = 1; i < E_EXP; ++i) if (row0 >= offs[i]) e = i;
    const u16* Bt = BtBase + (size_t)e * D_DIM * F_DIM;
    int k_begin = z * kPer;
    int k_end = k_begin + kPer;

    extern __shared__ __align__(16) u16 smem[];
    u16* As = smem;                  // [2][128*64]
    u16* Bs = smem + 2 * ABUF;       // [2][256*64]

    int tid = threadIdx.x;
    int lane = tid & 63;
    int wv = tid >> 6;               // 0..7
    int wm = wv & 1;                 // 2 M-halves (64 rows each)
    int wn = wv >> 1;                // 4 N-quarters (64 cols each)
    int kq = lane >> 4;              // quad 0..3
    int l15 = lane & 15;

    // staging: A = 2 x 512 slots, B = 4 x 512 slots; slot -> (m = slot>>3,
    // kc = slot&7). LDS dest LINEAR slot*16B; global col pre-swizzled.
    const u16* aS[2]; int aOff[2];
    const u16* bS[4]; int bOff[4];
#pragma unroll
    for (int i = 0; i < 2; ++i) {
        int slot = i * 512 + tid;
        int m = slot >> 3;
        int kcs = (slot & 7) ^ (m & 7);
        aS[i] = A + (size_t)(row0 + m) * lda + kcs * 8;
        aOff[i] = slot * 8;
    }
#pragma unroll
    for (int i = 0; i < 4; ++i) {
        int slot = i * 512 + tid;
        int m = slot >> 3;
        int kcs = (slot & 7) ^ (m & 7);
        bS[i] = Bt + (size_t)(n0 + m) * ldb + kcs * 8;
        bOff[i] = slot * 8;
    }

    auto stage = [&](int buf, int k0) {
#pragma unroll
        for (int i = 0; i < 2; ++i) gload16(As + buf * ABUF + aOff[i], aS[i] + k0);
#pragma unroll
        for (int i = 0; i < 4; ++i) gload16(Bs + buf * BBUF + bOff[i], bS[i] + k0);
    };

    f32x4 acc[4][4];
#pragma unroll
    for (int i = 0; i < 4; ++i)
#pragma unroll
        for (int j = 0; j < 4; ++j) acc[i][j] = f32x4{0.f, 0.f, 0.f, 0.f};

    // prologue: fill buffer 0
    stage(0, k_begin);
    asm volatile("s_waitcnt vmcnt(0)" ::: "memory");
    __syncthreads();

    int sx = l15 & 7;                // row&7 == l15&7 (wm*64, wn*64, i*16 ≡ 0 mod 8)
    int cur = 0;
    for (int k0 = k_begin; k0 < k_end; k0 += 64) {
        int kn = k0 + 64;
        if (kn < k_end) stage(cur ^ 1, kn);      // prefetch next K-step
        const u16* Ab = As + cur * ABUF;
        const u16* Bb = Bs + cur * BBUF;
#pragma unroll
        for (int kk = 0; kk < 2; ++kk) {
            int kc = kk * 4 + kq;
            int kca = kc ^ sx;       // swizzled column on the read side
            bf16x8 af[4], bfr[4];
#pragma unroll
            for (int i = 0; i < 4; ++i) {
                int rowA = wm * 64 + i * 16 + l15;
                af[i] = *(const bf16x8*)(Ab + rowA * 64 + kca * 8);
                int rowB = wn * 64 + i * 16 + l15;
                bfr[i] = *(const bf16x8*)(Bb + rowB * 64 + kca * 8);
            }
#pragma unroll
            for (int i = 0; i < 4; ++i)
#pragma unroll
                for (int j = 0; j < 4; ++j)
                    acc[i][j] = __builtin_amdgcn_mfma_f32_16x16x32_bf16(
                        af[i], bfr[j], acc[i][j], 0, 0, 0);
        }
        asm volatile("s_waitcnt vmcnt(0)" ::: "memory");
        __syncthreads();
        cur ^= 1;
    }

    if constexpr (MODE == 0) {
        const float* b1e = b1 + (size_t)e * F_DIM;
#pragma unroll
        for (int i = 0; i < 4; ++i) {
            int gr = row0 + wm * 64 + i * 16 + kq * 4;
#pragma unroll
            for (int j = 0; j < 4; ++j) {
                int gc = n0 + wn * 64 + j * 16 + l15;
                float bb = b1e[gc];
#pragma unroll
                for (int r = 0; r < 4; ++r) {
                    float v = acc[i][j][r] + bb;
                    Hout[(size_t)(gr + r) * F_DIM + gc] = f2b(gelu_f(v));
                }
            }
        }
    } else {
        const float* b2e = b2 + (size_t)e * D_DIM;
        bool addBias = (k_begin == 0);
#pragma unroll
        for (int i = 0; i < 4; ++i) {
            int grb = row0 + wm * 64 + i * 16 + kq * 4;
#pragma unroll
            for (int r = 0; r < 4; ++r) {
                int tok = rowmap[grb + r];
                float g = rowgate[grb + r];
                if (tok >= 0 && tok < T_TOK) {
                    float* orow = outm + (size_t)tok * D_DIM;
#pragma unroll
                    for (int j = 0; j < 4; ++j) {
                        int gc = n0 + wn * 64 + j * 16 + l15;
                        float bb = addBias ? b2e[gc] : 0.f;
                        atomicAdd(orow + gc, g * (acc[i][j][r] + bb));
                    }
                }
            }
        }
    }
}

// ---------------- workspace layout (bytes) — total need ~81 MB --------------
#define OFF_AN      0u           // 16 KB fp32 a_n
#define OFF_CNT     0x10000u
#define OFF_OFFS    0x10100u
#define OFF_IDX     0x20000u     // int[T*2]
#define OFF_GATE    0x28000u     // float[T*2]
#define OFF_ROWMAP  0x30000u     // int[NROWS]
#define OFF_ROWGATE 0x40000u     // float[NROWS]
#define OFF_XG      0x900000u    // 9.44 MB u16[NROWS*D]  -> ends 0x1200000
#define OFF_W1T     0x1200000u   // 16.78 MB u16[E][F][D] -> ends 0x2200000
#define OFF_W2T     0x2200000u   // 16.78 MB u16[E][D][F] -> ends 0x3200000
#define OFF_HG      0x3200000u   // 37.75 MB u16[NROWS*F] -> ends 0x5600000

#define GEMM_LDS (2 * (ABUF + BBUF) * 2)   // 98304 B = 96 KB

extern "C" void kernel_launch(void* const* d_in, const int* in_sizes, int n_in,
                              void* d_out, int out_size, void* d_ws, size_t ws_size,
                              hipStream_t stream) {
    const float* x       = (const float*)d_in[0];
    const float* anchors = (const float*)d_in[1];
    const float* W1      = (const float*)d_in[2];
    const float* b1      = (const float*)d_in[3];
    const float* W2      = (const float*)d_in[4];
    const float* b2      = (const float*)d_in[5];
    float* out = (float*)d_out;

    char* ws = (char*)d_ws;
    float* an      = (float*)(ws + OFF_AN);
    int*   cnt     = (int*)(ws + OFF_CNT);
    int*   offs    = (int*)(ws + OFF_OFFS);
    int*   idxs    = (int*)(ws + OFF_IDX);
    float* gates   = (float*)(ws + OFF_GATE);
    int*   rowmap  = (int*)(ws + OFF_ROWMAP);
    float* rowgate = (float*)(ws + OFF_ROWGATE);
    u16*   Xg      = (u16*)(ws + OFF_XG);
    u16*   W1T     = (u16*)(ws + OFF_W1T);
    u16*   W2T     = (u16*)(ws + OFF_W2T);
    u16*   Hg      = (u16*)(ws + OFF_HG);

    // d_out sections (fp32 elements): out | a_n | scores | topk_idx
    float* out_main   = out;
    float* out_an     = out + (size_t)T_TOK * D_DIM;
    float* out_scores = out_an + E_EXP * D_DIM;
    float* out_idx    = out_scores + (size_t)T_TOK * E_EXP;

    // allow 96 KB dynamic LDS (gfx950 has 160 KB/CU); once per process
    static bool attr_done = false;
    if (!attr_done) {
        hipFuncSetAttribute((const void*)gemm_k<0>,
                            hipFuncAttributeMaxDynamicSharedMemorySize, GEMM_LDS);
        hipFuncSetAttribute((const void*)gemm_k<1>,
                            hipFuncAttributeMaxDynamicSharedMemorySize, GEMM_LDS);
        attr_done = true;
    }

    init_k<<<512, 256, 0, stream>>>(cnt, rowmap, rowgate, out_main,
                                    anchors, an, out_an);
    routing_k<<<T_TOK / 64, 256, 0, stream>>>(x, an, out_scores, out_idx,
                                              idxs, gates, cnt);
    assign_k<<<1, 1024, 0, stream>>>(cnt, offs, idxs, gates, rowmap, rowgate);
    prep_k<<<PREP_BLOCKS, 256, 0, stream>>>(x, rowmap, Xg, W1, W1T, W2, W2T);
    // gemm1: 8 n-tiles(256) x 72 m-tiles(128) = 576 blocks (1D, XCD-swizzled)
    gemm_k<0><<<8 * MAXTILES, 512, GEMM_LDS, stream>>>(
        Xg, D_DIM, W1T, D_DIM, Hg, b1, nullptr, nullptr,
        rowmap, nullptr, offs, D_DIM, 8);
    // gemm2: 2 n-tiles(256) x 72 m-tiles x splitK2 = 288 blocks
    gemm_k<1><<<2 * MAXTILES * 2, 512, GEMM_LDS, stream>>>(
        Hg, F_DIM, W2T, F_DIM, nullptr, nullptr, out_main, b2,
        rowmap, rowgate, offs, F_DIM / 2, 2);
}

// Round 3
// 276.721 us; speedup vs baseline: 1.0128x; 1.0128x over previous
//
#include <hip/hip_runtime.h>
#include <cstdint>

// ---------------------------------------------------------------------------
// Round 16. r14/r15 post-mortem: both "2-phase" attempts drained vmcnt to 0
// every K-step -> only 48KB in flight per CU, no TLP (1 block/CU) -> memory
// system starved (2.4 TB/s achieved vs 4.6 in r13). Fix #1: REAL counted
// vmcnt (T4): 3 LDS buffers (144KB), depth-2 prefetch, vmcnt(6) per step,
// loads stay in flight across barriers. Fix #2: dispatch fusion 6->5: init_k
// killed; pre_k = [routing w/ in-block anchor-norm + per-block hist] +
// [W1/W2 transposes] + [outm zero]; assign_k sums hists + writes pad rows;
// prep_k -> gather-only. Predict: gemm 95 -> ~30 us, MfmaUtil 20-30%,
// FETCH ~30MB unchanged, total ~160-180 us.
// ---------------------------------------------------------------------------

#define T_TOK 4096
#define D_DIM 512
#define F_DIM 2048
#define E_EXP 8
#define NROWS 9216      // 8192 assignments + 8*128 pad
#define MAXTILES 72     // NROWS / 128

typedef __bf16 bf16x8 __attribute__((ext_vector_type(8)));
typedef float  f32x4  __attribute__((ext_vector_type(4)));
typedef unsigned short u16;

__device__ __forceinline__ u16 f2b(float f) {
    return __builtin_bit_cast(unsigned short, (__bf16)f);
}
__device__ __forceinline__ void gload16(void* lds, const void* g) {
    __builtin_amdgcn_global_load_lds(
        (const __attribute__((address_space(1))) void*)g,
        (__attribute__((address_space(3))) void*)lds, 16, 0, 0);
}
// tanh-approx GELU (err ~3e-4 << bf16 ulp)
__device__ __forceinline__ float gelu_f(float v) {
    float z = 0.7978845608f * (v + 0.044715f * v * v * v);
    float t = 1.0f - 2.0f / (1.0f + __expf(2.0f * z));
    return 0.5f * v * (1.0f + t);
}

// ---------------- transpose tile body (shared by pre_k) ---------------------
__device__ __forceinline__ void tbody(const float* __restrict__ in,
                                      u16* __restrict__ out, int R, int C,
                                      int c0, int r0, int tid,
                                      float (*t)[65]) {
    int cq = tid & 15, rb = tid >> 4;
#pragma unroll
    for (int pass = 0; pass < 4; ++pass) {
        int rr = rb + pass * 16;
        float4 v = *(const float4*)(in + (size_t)(r0 + rr) * C + c0 + cq * 4);
        t[rr][cq * 4 + 0] = v.x; t[rr][cq * 4 + 1] = v.y;
        t[rr][cq * 4 + 2] = v.z; t[rr][cq * 4 + 3] = v.w;
    }
    __syncthreads();
    int rg = tid & 15, cb = tid >> 4;
#pragma unroll
    for (int pass = 0; pass < 4; ++pass) {
        int c = cb + pass * 16;
        ushort4 o;
        o.x = f2b(t[rg * 4 + 0][c]); o.y = f2b(t[rg * 4 + 1][c]);
        o.z = f2b(t[rg * 4 + 2][c]); o.w = f2b(t[rg * 4 + 3][c]);
        *(ushort4*)(out + (size_t)(c0 + c) * R + r0 + rg * 4) = o;
    }
}

// ---------------- pre_k: routing + W-transposes + outm zero, ONE dispatch ---
// blocks [0,64): routing (in-block anchor norm, per-block hist -> cnthist)
// blocks [64,64+4096): W1/W2 transpose
// blocks [4160,4160+1024): zero outm (4096x512 f32)
#define RT_BLKS 64
#define TR_BLKS 4096
#define ZO_BLKS 1024
#define PRE_BLOCKS (RT_BLKS + TR_BLKS + ZO_BLKS)

__global__ void pre_k(const float* __restrict__ x, const float* __restrict__ anchors,
                      const float* __restrict__ W1, u16* __restrict__ W1T,
                      const float* __restrict__ W2, u16* __restrict__ W2T,
                      float* __restrict__ outm, float* __restrict__ dout_an,
                      float* __restrict__ dout_scores, float* __restrict__ dout_idx,
                      int* __restrict__ idxs, float* __restrict__ gates,
                      int* __restrict__ cnthist) {
    __shared__ float shpool[E_EXP * 544];   // routing: anl; transpose: 64x65
    __shared__ int hist[E_EXP];
    int b = blockIdx.x;
    int tid = threadIdx.x;

    if (b >= RT_BLKS + TR_BLKS) {           // ---- zero outm ----
        int zb = b - (RT_BLKS + TR_BLKS);
        float4* o4 = (float4*)outm;
        int i = zb * 256 + tid;             // 262144 threads x 2 float4
        o4[i] = float4{0.f, 0.f, 0.f, 0.f};
        o4[i + ZO_BLKS * 256] = float4{0.f, 0.f, 0.f, 0.f};
        return;
    }
    if (b >= RT_BLKS) {                     // ---- transposes ----
        float (*tsh)[65] = (float(*)[65])shpool;   // 4160 floats <= 4352
        int tt = b - RT_BLKS;
        if (tt < 2048) {                    // W1 [E][512][2048] -> [E][2048][512]
            int bx = tt & 31, by = (tt >> 5) & 7, bz = tt >> 8;
            size_t zoff = (size_t)bz * D_DIM * F_DIM;
            tbody(W1 + zoff, W1T + zoff, D_DIM, F_DIM, bx * 64, by * 64, tid, tsh);
        } else {                            // W2 [E][2048][512] -> [E][512][2048]
            int t2 = tt - 2048;
            int bx = t2 & 7, by = (t2 >> 3) & 31, bz = t2 >> 8;
            size_t zoff = (size_t)bz * D_DIM * F_DIM;
            tbody(W2 + zoff, W2T + zoff, F_DIM, D_DIM, bx * 64, by * 64, tid, tsh);
        }
        return;
    }

    // ---- routing ----
    float* anl = shpool;                    // [e][p*136 + i], i<128
    if (tid < E_EXP) hist[tid] = 0;
    for (int i = tid; i < E_EXP * D_DIM; i += 256) {
        int e = i >> 9, d = i & 511;
        anl[e * 544 + (d >> 7) * 136 + (d & 127)] = anchors[i];
    }
    __syncthreads();
    {   // normalize anchors in LDS: 32 threads per anchor
        int e = tid >> 5, l = tid & 31;
        float ss = 0.f;
        for (int d = l; d < D_DIM; d += 32) {
            float v = anl[e * 544 + (d >> 7) * 136 + (d & 127)];
            ss += v * v;
        }
#pragma unroll
        for (int off = 16; off >= 1; off >>= 1) ss += __shfl_xor(ss, off, 32);
        float inv = 1.0f / fmaxf(sqrtf(ss), 1e-8f);
        for (int d = l; d < D_DIM; d += 32) {
            int ix = e * 544 + (d >> 7) * 136 + (d & 127);
            float nv = anl[ix] * inv;
            anl[ix] = nv;
            if (b == 0) dout_an[e * D_DIM + d] = nv;
        }
    }
    __syncthreads();

    int p = tid & 3;
    int tok = b * 64 + (tid >> 2);
    const float4* xr = (const float4*)(x + (size_t)tok * D_DIM + p * 128);
    const float* ab = &anl[p * 136];
    float dot[E_EXP] = {};
    float ss = 0.f;
    for (int c = 0; c < 32; ++c) {
        float4 xv = xr[c];
        ss += xv.x*xv.x + xv.y*xv.y + xv.z*xv.z + xv.w*xv.w;
#pragma unroll
        for (int e = 0; e < E_EXP; ++e) {
            float4 av = *(const float4*)&ab[e * 544 + c * 4];
            dot[e] += xv.x*av.x + xv.y*av.y + xv.z*av.z + xv.w*av.w;
        }
    }
#pragma unroll
    for (int off = 1; off <= 2; off <<= 1) {
        ss += __shfl_xor(ss, off, 64);
#pragma unroll
        for (int e = 0; e < E_EXP; ++e) dot[e] += __shfl_xor(dot[e], off, 64);
    }

    if (p == 0) {
        float inv = 1.0f / fmaxf(sqrtf(ss), 1e-8f);
        float s[E_EXP];
#pragma unroll
        for (int e = 0; e < E_EXP; ++e) s[e] = dot[e] * inv;
        int i0 = 0; float b0 = s[0];
#pragma unroll
        for (int e = 1; e < E_EXP; ++e) if (s[e] > b0) { b0 = s[e]; i0 = e; }
        int i1 = -1; float b1v = -1e30f;
#pragma unroll
        for (int e = 0; e < E_EXP; ++e)
            if (e != i0 && s[e] > b1v) { b1v = s[e]; i1 = e; }
        if (i1 < 0) { i1 = (i0 + 1) & 7; b1v = s[i1]; }   // NaN-safety
        float g0 = 1.0f / (1.0f + expf(b1v - b0));
        float g1 = 1.0f - g0;
#pragma unroll
        for (int e = 0; e < E_EXP; ++e) dout_scores[tok * E_EXP + e] = s[e];
        dout_idx[tok * 2 + 0] = (float)i0;
        dout_idx[tok * 2 + 1] = (float)i1;
        idxs[tok * 2 + 0] = i0; idxs[tok * 2 + 1] = i1;
        gates[tok * 2 + 0] = g0; gates[tok * 2 + 1] = g1;
        atomicAdd(&hist[i0], 1);
        atomicAdd(&hist[i1], 1);
    }
    __syncthreads();
    if (tid < E_EXP) cnthist[b * E_EXP + tid] = hist[tid];
}

// ---------------- offsets + slot assignment + pad rows, ONE block -----------
__global__ void assign_k(const int* __restrict__ cnthist, int* __restrict__ offs,
                         const int* __restrict__ idxs, const float* __restrict__ gates,
                         int* __restrict__ rowmap, float* __restrict__ rowgate) {
    __shared__ int scur[E_EXP];
    __shared__ int soff[E_EXP + 1];
    __shared__ int scnt[E_EXP];
    int tid = threadIdx.x;
    if (tid < E_EXP) {                      // sum 64 per-block histograms
        int s = 0;
        for (int b = 0; b < RT_BLKS; ++b) s += cnthist[b * E_EXP + tid];
        scnt[tid] = s;
    }
    __syncthreads();
    if (tid == 0) {
        int acc = 0;
        for (int e = 0; e < E_EXP; ++e) {
            soff[e] = acc; offs[e] = acc; scur[e] = acc;
            acc += (scnt[e] + 127) & ~127;
        }
        soff[E_EXP] = acc; offs[E_EXP] = acc;
    }
    __syncthreads();
    for (int t = tid; t < T_TOK; t += 1024) {
#pragma unroll
        for (int k = 0; k < 2; ++k) {
            int e = idxs[t * 2 + k];
            e = min(max(e, 0), E_EXP - 1);
            int r = atomicAdd(&scur[e], 1);
            if (r >= 0 && r < NROWS) {
                rowmap[r] = t;
                rowgate[r] = gates[t * 2 + k];
            }
        }
    }
    __syncthreads();
    // pad rows [offs[e]+cnt[e], offs[e+1]) -> rowmap=-1, rowgate=0
#pragma unroll
    for (int e = 0; e < E_EXP; ++e) {
        int s = soff[e] + scnt[e];
        int fin = soff[e + 1];
        for (int r = s + tid; r < fin; r += 1024) {
            rowmap[r] = -1; rowgate[r] = 0.f;
        }
    }
}

// ---------------- gather: Xg rows from x via rowmap -------------------------
__global__ void gather_k(const float* __restrict__ x, const int* __restrict__ rowmap,
                         u16* __restrict__ Xg) {
    int b = blockIdx.x;
    int tid = threadIdx.x;
    int t = rowmap[b];
    int c = tid * 2;
    ushort2 o;
    if (t < 0 || t >= T_TOK) { o.x = 0; o.y = 0; }
    else {
        float2 v = *(const float2*)(x + (size_t)t * D_DIM + c);
        o.x = f2b(v.x); o.y = f2b(v.y);
    }
    *(ushort2*)(Xg + (size_t)b * D_DIM + c) = o;
}

// ---------------- grouped GEMM core (r16: 3-buf counted-vmcnt pipeline) -----
// MODE 0: Hg = bf16(gelu(Xg @ W1e^T + b1e))         (N=F, K=D), nT=8
// MODE 1: out[tok] += gate*(Hg @ W2e^T + [z0]b2e)   (N=D, K=F, split-K=2), nT=2
// 128x256 tile, 8 waves (2m x 4n, 64x64/wave). LDS = 3 bufs x 48KB = 144KB.
// Depth-2 prefetch: stage t0,t1; loop { vmcnt(6 | 0 last); barrier;
// stage(t+2); compute(t) }. Loads stay in flight ACROSS barriers (T4).
// XOR col swizzle kc^(row&7): global source pre-swizzled, read side XORed.
#define ABUF (128 * 64)
#define BBUF (256 * 64)
#define GEMM_LDS (3 * (ABUF + BBUF) * 2)   // 147456 B = 144 KB
template <int MODE>
__launch_bounds__(512, 2)
__global__ void gemm_k(const u16* __restrict__ A, int lda,
                       const u16* __restrict__ BtBase, int ldb,
                       u16* __restrict__ Hout, const float* __restrict__ b1,
                       float* __restrict__ outm, const float* __restrict__ b2,
                       const int* __restrict__ rowmap, const float* __restrict__ rowgate,
                       const int* __restrict__ offs, int kPer, int nT) {
    int L = blockIdx.x;
    int per = gridDim.x >> 3;
    int tile = (L & 7) * per + (L >> 3);
    int z = 0;
    if (MODE == 1) {                 // split-K 2: high half of tiles is z=1
        int half = gridDim.x >> 1;
        z = tile >= half; tile -= z * half;
    }
    int mtile = tile / nT;
    int n0 = (tile - mtile * nT) * 256;
    int row0 = mtile * 128;
    if (row0 >= offs[E_EXP]) return;
    int e = 0;
#pragma unroll
    for (int i = 1; i < E_EXP; ++i) if (row0 >= offs[i]) e = i;
    const u16* Bt = BtBase + (size_t)e * D_DIM * F_DIM;
    int k_begin = z * kPer;
    int nt = kPer >> 6;              // K-tiles

    extern __shared__ __align__(16) u16 smem[];
    u16* As = smem;                  // [3][128*64]
    u16* Bs = smem + 3 * ABUF;       // [3][256*64]

    int tid = threadIdx.x;
    int lane = tid & 63;
    int wv = tid >> 6;               // 0..7
    int wm = wv & 1;                 // 2 M-halves (64 rows each)
    int wn = wv >> 1;                // 4 N-quarters (64 cols each)
    int kq = lane >> 4;              // quad 0..3
    int l15 = lane & 15;

    // staging: A = 2 x 512 slots, B = 4 x 512 slots; slot -> (m = slot>>3,
    // kc = slot&7). LDS dest LINEAR slot*16B; global col pre-swizzled.
    const u16* aS[2]; int aOff[2];
    const u16* bS[4]; int bOff[4];
#pragma unroll
    for (int i = 0; i < 2; ++i) {
        int slot = i * 512 + tid;
        int m = slot >> 3;
        int kcs = (slot & 7) ^ (m & 7);
        aS[i] = A + (size_t)(row0 + m) * lda + kcs * 8;
        aOff[i] = slot * 8;
    }
#pragma unroll
    for (int i = 0; i < 4; ++i) {
        int slot = i * 512 + tid;
        int m = slot >> 3;
        int kcs = (slot & 7) ^ (m & 7);
        bS[i] = Bt + (size_t)(n0 + m) * ldb + kcs * 8;
        bOff[i] = slot * 8;
    }

    auto stage = [&](int buf, int k0) {
#pragma unroll
        for (int i = 0; i < 2; ++i) gload16(As + buf * ABUF + aOff[i], aS[i] + k0);
#pragma unroll
        for (int i = 0; i < 4; ++i) gload16(Bs + buf * BBUF + bOff[i], bS[i] + k0);
    };

    f32x4 acc[4][4];
#pragma unroll
    for (int i = 0; i < 4; ++i)
#pragma unroll
        for (int j = 0; j < 4; ++j) acc[i][j] = f32x4{0.f, 0.f, 0.f, 0.f};

    // prologue: 2 tiles in flight (12 outstanding gload_lds per wave)
    stage(0, k_begin);
    if (nt > 1) stage(1, k_begin + 64);

    int sx = l15 & 7;                // row&7 == l15&7 (wm*64, wn*64, i*16 ≡ 0 mod 8)
    int bi = 0;                      // compute buffer = t%3
    int st = 2;                      // stage buffer   = (t+2)%3
    for (int t = 0; t < nt; ++t) {
        // wait ONLY for tile t's 6 loads; tile t+1 stays in flight (T4)
        if (t < nt - 1) asm volatile("s_waitcnt vmcnt(6)" ::: "memory");
        else            asm volatile("s_waitcnt vmcnt(0)" ::: "memory");
        __syncthreads();
        if (t + 2 < nt) stage(st, k_begin + (t + 2) * 64);   // buffer freed at t-1
        const u16* Ab = As + bi * ABUF;
        const u16* Bb = Bs + bi * BBUF;
        __builtin_amdgcn_s_setprio(1);
#pragma unroll
        for (int kk = 0; kk < 2; ++kk) {
            int kc = kk * 4 + kq;
            int kca = kc ^ sx;       // swizzled column on the read side
            bf16x8 af[4], bfr[4];
#pragma unroll
            for (int i = 0; i < 4; ++i) {
                int rowA = wm * 64 + i * 16 + l15;
                af[i] = *(const bf16x8*)(Ab + rowA * 64 + kca * 8);
                int rowB = wn * 64 + i * 16 + l15;
                bfr[i] = *(const bf16x8*)(Bb + rowB * 64 + kca * 8);
            }
#pragma unroll
            for (int i = 0; i < 4; ++i)
#pragma unroll
                for (int j = 0; j < 4; ++j)
                    acc[i][j] = __builtin_amdgcn_mfma_f32_16x16x32_bf16(
                        af[i], bfr[j], acc[i][j], 0, 0, 0);
        }
        __builtin_amdgcn_s_setprio(0);
        bi = (bi == 2) ? 0 : bi + 1;
        st = (st == 2) ? 0 : st + 1;
    }

    if constexpr (MODE == 0) {
        const float* b1e = b1 + (size_t)e * F_DIM;
#pragma unroll
        for (int i = 0; i < 4; ++i) {
            int gr = row0 + wm * 64 + i * 16 + kq * 4;
#pragma unroll
            for (int j = 0; j < 4; ++j) {
                int gc = n0 + wn * 64 + j * 16 + l15;
                float bb = b1e[gc];
#pragma unroll
                for (int r = 0; r < 4; ++r) {
                    float v = acc[i][j][r] + bb;
                    Hout[(size_t)(gr + r) * F_DIM + gc] = f2b(gelu_f(v));
                }
            }
        }
    } else {
        const float* b2e = b2 + (size_t)e * D_DIM;
        bool addBias = (k_begin == 0);
#pragma unroll
        for (int i = 0; i < 4; ++i) {
            int grb = row0 + wm * 64 + i * 16 + kq * 4;
#pragma unroll
            for (int r = 0; r < 4; ++r) {
                int tok = rowmap[grb + r];
                float g = rowgate[grb + r];
                if (tok >= 0 && tok < T_TOK) {
                    float* orow = outm + (size_t)tok * D_DIM;
#pragma unroll
                    for (int j = 0; j < 4; ++j) {
                        int gc = n0 + wn * 64 + j * 16 + l15;
                        float bb = addBias ? b2e[gc] : 0.f;
                        atomicAdd(orow + gc, g * (acc[i][j][r] + bb));
                    }
                }
            }
        }
    }
}

// ---------------- workspace layout (bytes) ----------------------------------
#define OFF_CNTH    0x10000u     // int[64*8] per-block histograms
#define OFF_OFFS    0x10900u     // int[9]
#define OFF_IDX     0x20000u     // int[T*2]
#define OFF_GATE    0x28000u     // float[T*2]
#define OFF_ROWMAP  0x30000u     // int[NROWS]
#define OFF_ROWGATE 0x40000u     // float[NROWS]
#define OFF_XG      0x900000u    // 9.44 MB u16[NROWS*D]  -> ends 0x1200000
#define OFF_W1T     0x1200000u   // 16.78 MB u16[E][F][D] -> ends 0x2200000
#define OFF_W2T     0x2200000u   // 16.78 MB u16[E][D][F] -> ends 0x3200000
#define OFF_HG      0x3200000u   // 37.75 MB u16[NROWS*F] -> ends 0x5600000

extern "C" void kernel_launch(void* const* d_in, const int* in_sizes, int n_in,
                              void* d_out, int out_size, void* d_ws, size_t ws_size,
                              hipStream_t stream) {
    const float* x       = (const float*)d_in[0];
    const float* anchors = (const float*)d_in[1];
    const float* W1      = (const float*)d_in[2];
    const float* b1      = (const float*)d_in[3];
    const float* W2      = (const float*)d_in[4];
    const float* b2      = (const float*)d_in[5];
    float* out = (float*)d_out;

    char* ws = (char*)d_ws;
    int*   cnthist = (int*)(ws + OFF_CNTH);
    int*   offs    = (int*)(ws + OFF_OFFS);
    int*   idxs    = (int*)(ws + OFF_IDX);
    float* gates   = (float*)(ws + OFF_GATE);
    int*   rowmap  = (int*)(ws + OFF_ROWMAP);
    float* rowgate = (float*)(ws + OFF_ROWGATE);
    u16*   Xg      = (u16*)(ws + OFF_XG);
    u16*   W1T     = (u16*)(ws + OFF_W1T);
    u16*   W2T     = (u16*)(ws + OFF_W2T);
    u16*   Hg      = (u16*)(ws + OFF_HG);

    // d_out sections (fp32 elements): out | a_n | scores | topk_idx
    float* out_main   = out;
    float* out_an     = out + (size_t)T_TOK * D_DIM;
    float* out_scores = out_an + E_EXP * D_DIM;
    float* out_idx    = out_scores + (size_t)T_TOK * E_EXP;

    // allow 144 KB dynamic LDS (gfx950 has 160 KB/CU); once per process
    static bool attr_done = false;
    if (!attr_done) {
        hipFuncSetAttribute((const void*)gemm_k<0>,
                            hipFuncAttributeMaxDynamicSharedMemorySize, GEMM_LDS);
        hipFuncSetAttribute((const void*)gemm_k<1>,
                            hipFuncAttributeMaxDynamicSharedMemorySize, GEMM_LDS);
        attr_done = true;
    }

    pre_k<<<PRE_BLOCKS, 256, 0, stream>>>(x, anchors, W1, W1T, W2, W2T,
                                          out_main, out_an, out_scores, out_idx,
                                          idxs, gates, cnthist);
    assign_k<<<1, 1024, 0, stream>>>(cnthist, offs, idxs, gates, rowmap, rowgate);
    gather_k<<<NROWS, 256, 0, stream>>>(x, rowmap, Xg);
    // gemm1: 8 n-tiles(256) x 72 m-tiles(128) = 576 blocks (1D, XCD-swizzled)
    gemm_k<0><<<8 * MAXTILES, 512, GEMM_LDS, stream>>>(
        Xg, D_DIM, W1T, D_DIM, Hg, b1, nullptr, nullptr,
        rowmap, nullptr, offs, D_DIM, 8);
    // gemm2: 2 n-tiles(256) x 72 m-tiles x splitK2 = 288 blocks
    gemm_k<1><<<2 * MAXTILES * 2, 512, GEMM_LDS, stream>>>(
        Hg, F_DIM, W2T, F_DIM, nullptr, nullptr, out_main, b2,
        rowmap, rowgate, offs, F_DIM / 2, 2);
}

// Round 4
// 274.802 us; speedup vs baseline: 1.0199x; 1.0070x over previous
//
#include <hip/hip_runtime.h>
#include <cstdint>

// ---------------------------------------------------------------------------
// Round 17. r16 post-mortem: counted vmcnt(6) was a NO-OP because
// __syncthreads() emits "s_waitcnt vmcnt(0) lgkmcnt(0)" before s_barrier
// (HIP semantics) -> pipeline drained every K-step anyway. r14/r15/r16 were
// all secretly the same drain-to-0 schedule. Single causal fix this round:
// RAW __builtin_amdgcn_s_barrier() (+ sched_barrier(0) fence, rule 18) in
// the gemm K-loop, keeping vmcnt(6) counted waits. 12 loads / 96KB per CU
// stay in flight across barriers (true T3+T4).
// Predict: gemm 94 -> 25-40 us each, MfmaUtil 20-30%, FETCH ~30MB unchanged,
// total ~150-175 us. If unchanged -> r18 reg-staged ds_write path.
// ---------------------------------------------------------------------------

#define T_TOK 4096
#define D_DIM 512
#define F_DIM 2048
#define E_EXP 8
#define NROWS 9216      // 8192 assignments + 8*128 pad
#define MAXTILES 72     // NROWS / 128

typedef __bf16 bf16x8 __attribute__((ext_vector_type(8)));
typedef float  f32x4  __attribute__((ext_vector_type(4)));
typedef unsigned short u16;

__device__ __forceinline__ u16 f2b(float f) {
    return __builtin_bit_cast(unsigned short, (__bf16)f);
}
__device__ __forceinline__ void gload16(void* lds, const void* g) {
    __builtin_amdgcn_global_load_lds(
        (const __attribute__((address_space(1))) void*)g,
        (__attribute__((address_space(3))) void*)lds, 16, 0, 0);
}
// tanh-approx GELU (err ~3e-4 << bf16 ulp)
__device__ __forceinline__ float gelu_f(float v) {
    float z = 0.7978845608f * (v + 0.044715f * v * v * v);
    float t = 1.0f - 2.0f / (1.0f + __expf(2.0f * z));
    return 0.5f * v * (1.0f + t);
}

// ---------------- transpose tile body (shared by pre_k) ---------------------
__device__ __forceinline__ void tbody(const float* __restrict__ in,
                                      u16* __restrict__ out, int R, int C,
                                      int c0, int r0, int tid,
                                      float (*t)[65]) {
    int cq = tid & 15, rb = tid >> 4;
#pragma unroll
    for (int pass = 0; pass < 4; ++pass) {
        int rr = rb + pass * 16;
        float4 v = *(const float4*)(in + (size_t)(r0 + rr) * C + c0 + cq * 4);
        t[rr][cq * 4 + 0] = v.x; t[rr][cq * 4 + 1] = v.y;
        t[rr][cq * 4 + 2] = v.z; t[rr][cq * 4 + 3] = v.w;
    }
    __syncthreads();
    int rg = tid & 15, cb = tid >> 4;
#pragma unroll
    for (int pass = 0; pass < 4; ++pass) {
        int c = cb + pass * 16;
        ushort4 o;
        o.x = f2b(t[rg * 4 + 0][c]); o.y = f2b(t[rg * 4 + 1][c]);
        o.z = f2b(t[rg * 4 + 2][c]); o.w = f2b(t[rg * 4 + 3][c]);
        *(ushort4*)(out + (size_t)(c0 + c) * R + r0 + rg * 4) = o;
    }
}

// ---------------- pre_k: routing + W-transposes + outm zero, ONE dispatch ---
// blocks [0,64): routing (in-block anchor norm, per-block hist -> cnthist)
// blocks [64,64+4096): W1/W2 transpose
// blocks [4160,4160+1024): zero outm (4096x512 f32)
#define RT_BLKS 64
#define TR_BLKS 4096
#define ZO_BLKS 1024
#define PRE_BLOCKS (RT_BLKS + TR_BLKS + ZO_BLKS)

__global__ void pre_k(const float* __restrict__ x, const float* __restrict__ anchors,
                      const float* __restrict__ W1, u16* __restrict__ W1T,
                      const float* __restrict__ W2, u16* __restrict__ W2T,
                      float* __restrict__ outm, float* __restrict__ dout_an,
                      float* __restrict__ dout_scores, float* __restrict__ dout_idx,
                      int* __restrict__ idxs, float* __restrict__ gates,
                      int* __restrict__ cnthist) {
    __shared__ float shpool[E_EXP * 544];   // routing: anl; transpose: 64x65
    __shared__ int hist[E_EXP];
    int b = blockIdx.x;
    int tid = threadIdx.x;

    if (b >= RT_BLKS + TR_BLKS) {           // ---- zero outm ----
        int zb = b - (RT_BLKS + TR_BLKS);
        float4* o4 = (float4*)outm;
        int i = zb * 256 + tid;             // 262144 threads x 2 float4
        o4[i] = float4{0.f, 0.f, 0.f, 0.f};
        o4[i + ZO_BLKS * 256] = float4{0.f, 0.f, 0.f, 0.f};
        return;
    }
    if (b >= RT_BLKS) {                     // ---- transposes ----
        float (*tsh)[65] = (float(*)[65])shpool;   // 4160 floats <= 4352
        int tt = b - RT_BLKS;
        if (tt < 2048) {                    // W1 [E][512][2048] -> [E][2048][512]
            int bx = tt & 31, by = (tt >> 5) & 7, bz = tt >> 8;
            size_t zoff = (size_t)bz * D_DIM * F_DIM;
            tbody(W1 + zoff, W1T + zoff, D_DIM, F_DIM, bx * 64, by * 64, tid, tsh);
        } else {                            // W2 [E][2048][512] -> [E][512][2048]
            int t2 = tt - 2048;
            int bx = t2 & 7, by = (t2 >> 3) & 31, bz = t2 >> 8;
            size_t zoff = (size_t)bz * D_DIM * F_DIM;
            tbody(W2 + zoff, W2T + zoff, F_DIM, D_DIM, bx * 64, by * 64, tid, tsh);
        }
        return;
    }

    // ---- routing ----
    float* anl = shpool;                    // [e][p*136 + i], i<128
    if (tid < E_EXP) hist[tid] = 0;
    for (int i = tid; i < E_EXP * D_DIM; i += 256) {
        int e = i >> 9, d = i & 511;
        anl[e * 544 + (d >> 7) * 136 + (d & 127)] = anchors[i];
    }
    __syncthreads();
    {   // normalize anchors in LDS: 32 threads per anchor
        int e = tid >> 5, l = tid & 31;
        float ss = 0.f;
        for (int d = l; d < D_DIM; d += 32) {
            float v = anl[e * 544 + (d >> 7) * 136 + (d & 127)];
            ss += v * v;
        }
#pragma unroll
        for (int off = 16; off >= 1; off >>= 1) ss += __shfl_xor(ss, off, 32);
        float inv = 1.0f / fmaxf(sqrtf(ss), 1e-8f);
        for (int d = l; d < D_DIM; d += 32) {
            int ix = e * 544 + (d >> 7) * 136 + (d & 127);
            float nv = anl[ix] * inv;
            anl[ix] = nv;
            if (b == 0) dout_an[e * D_DIM + d] = nv;
        }
    }
    __syncthreads();

    int p = tid & 3;
    int tok = b * 64 + (tid >> 2);
    const float4* xr = (const float4*)(x + (size_t)tok * D_DIM + p * 128);
    const float* ab = &anl[p * 136];
    float dot[E_EXP] = {};
    float ss = 0.f;
    for (int c = 0; c < 32; ++c) {
        float4 xv = xr[c];
        ss += xv.x*xv.x + xv.y*xv.y + xv.z*xv.z + xv.w*xv.w;
#pragma unroll
        for (int e = 0; e < E_EXP; ++e) {
            float4 av = *(const float4*)&ab[e * 544 + c * 4];
            dot[e] += xv.x*av.x + xv.y*av.y + xv.z*av.z + xv.w*av.w;
        }
    }
#pragma unroll
    for (int off = 1; off <= 2; off <<= 1) {
        ss += __shfl_xor(ss, off, 64);
#pragma unroll
        for (int e = 0; e < E_EXP; ++e) dot[e] += __shfl_xor(dot[e], off, 64);
    }

    if (p == 0) {
        float inv = 1.0f / fmaxf(sqrtf(ss), 1e-8f);
        float s[E_EXP];
#pragma unroll
        for (int e = 0; e < E_EXP; ++e) s[e] = dot[e] * inv;
        int i0 = 0; float b0 = s[0];
#pragma unroll
        for (int e = 1; e < E_EXP; ++e) if (s[e] > b0) { b0 = s[e]; i0 = e; }
        int i1 = -1; float b1v = -1e30f;
#pragma unroll
        for (int e = 0; e < E_EXP; ++e)
            if (e != i0 && s[e] > b1v) { b1v = s[e]; i1 = e; }
        if (i1 < 0) { i1 = (i0 + 1) & 7; b1v = s[i1]; }   // NaN-safety
        float g0 = 1.0f / (1.0f + expf(b1v - b0));
        float g1 = 1.0f - g0;
#pragma unroll
        for (int e = 0; e < E_EXP; ++e) dout_scores[tok * E_EXP + e] = s[e];
        dout_idx[tok * 2 + 0] = (float)i0;
        dout_idx[tok * 2 + 1] = (float)i1;
        idxs[tok * 2 + 0] = i0; idxs[tok * 2 + 1] = i1;
        gates[tok * 2 + 0] = g0; gates[tok * 2 + 1] = g1;
        atomicAdd(&hist[i0], 1);
        atomicAdd(&hist[i1], 1);
    }
    __syncthreads();
    if (tid < E_EXP) cnthist[b * E_EXP + tid] = hist[tid];
}

// ---------------- offsets + slot assignment + pad rows, ONE block -----------
__global__ void assign_k(const int* __restrict__ cnthist, int* __restrict__ offs,
                         const int* __restrict__ idxs, const float* __restrict__ gates,
                         int* __restrict__ rowmap, float* __restrict__ rowgate) {
    __shared__ int scur[E_EXP];
    __shared__ int soff[E_EXP + 1];
    __shared__ int scnt[E_EXP];
    int tid = threadIdx.x;
    if (tid < E_EXP) {                      // sum 64 per-block histograms
        int s = 0;
        for (int b = 0; b < RT_BLKS; ++b) s += cnthist[b * E_EXP + tid];
        scnt[tid] = s;
    }
    __syncthreads();
    if (tid == 0) {
        int acc = 0;
        for (int e = 0; e < E_EXP; ++e) {
            soff[e] = acc; offs[e] = acc; scur[e] = acc;
            acc += (scnt[e] + 127) & ~127;
        }
        soff[E_EXP] = acc; offs[E_EXP] = acc;
    }
    __syncthreads();
    for (int t = tid; t < T_TOK; t += 1024) {
#pragma unroll
        for (int k = 0; k < 2; ++k) {
            int e = idxs[t * 2 + k];
            e = min(max(e, 0), E_EXP - 1);
            int r = atomicAdd(&scur[e], 1);
            if (r >= 0 && r < NROWS) {
                rowmap[r] = t;
                rowgate[r] = gates[t * 2 + k];
            }
        }
    }
    __syncthreads();
    // pad rows [offs[e]+cnt[e], offs[e+1]) -> rowmap=-1, rowgate=0
#pragma unroll
    for (int e = 0; e < E_EXP; ++e) {
        int s = soff[e] + scnt[e];
        int fin = soff[e + 1];
        for (int r = s + tid; r < fin; r += 1024) {
            rowmap[r] = -1; rowgate[r] = 0.f;
        }
    }
}

// ---------------- gather: Xg rows from x via rowmap -------------------------
__global__ void gather_k(const float* __restrict__ x, const int* __restrict__ rowmap,
                         u16* __restrict__ Xg) {
    int b = blockIdx.x;
    int tid = threadIdx.x;
    int t = rowmap[b];
    int c = tid * 2;
    ushort2 o;
    if (t < 0 || t >= T_TOK) { o.x = 0; o.y = 0; }
    else {
        float2 v = *(const float2*)(x + (size_t)t * D_DIM + c);
        o.x = f2b(v.x); o.y = f2b(v.y);
    }
    *(ushort2*)(Xg + (size_t)b * D_DIM + c) = o;
}

// ---------------- grouped GEMM core (r17: RAW-barrier counted pipeline) -----
// MODE 0: Hg = bf16(gelu(Xg @ W1e^T + b1e))         (N=F, K=D), nT=8
// MODE 1: out[tok] += gate*(Hg @ W2e^T + [z0]b2e)   (N=D, K=F, split-K=2), nT=2
// 128x256 tile, 8 waves (2m x 4n, 64x64/wave). LDS = 3 bufs x 48KB = 144KB.
// Depth-2 prefetch: stage t0,t1; loop { vmcnt(6|0); RAW s_barrier;
// sched_barrier(0); stage(t+2); compute(t) }. Loads stay in flight ACROSS
// barriers — __syncthreads would drain vmcnt to 0 (r16 bug), raw barrier
// does not. XOR col swizzle kc^(row&7) both sides (conflict-free, r14).
#define ABUF (128 * 64)
#define BBUF (256 * 64)
#define GEMM_LDS (3 * (ABUF + BBUF) * 2)   // 147456 B = 144 KB
template <int MODE>
__launch_bounds__(512, 2)
__global__ void gemm_k(const u16* __restrict__ A, int lda,
                       const u16* __restrict__ BtBase, int ldb,
                       u16* __restrict__ Hout, const float* __restrict__ b1,
                       float* __restrict__ outm, const float* __restrict__ b2,
                       const int* __restrict__ rowmap, const float* __restrict__ rowgate,
                       const int* __restrict__ offs, int kPer, int nT) {
    int L = blockIdx.x;
    int per = gridDim.x >> 3;
    int tile = (L & 7) * per + (L >> 3);
    int z = 0;
    if (MODE == 1) {                 // split-K 2: high half of tiles is z=1
        int half = gridDim.x >> 1;
        z = tile >= half; tile -= z * half;
    }
    int mtile = tile / nT;
    int n0 = (tile - mtile * nT) * 256;
    int row0 = mtile * 128;
    if (row0 >= offs[E_EXP]) return;
    int e = 0;
#pragma unroll
    for (int i = 1; i < E_EXP; ++i) if (row0 >= offs[i]) e = i;
    const u16* Bt = BtBase + (size_t)e * D_DIM * F_DIM;
    int k_begin = z * kPer;
    int nt = kPer >> 6;              // K-tiles

    extern __shared__ __align__(16) u16 smem[];
    u16* As = smem;                  // [3][128*64]
    u16* Bs = smem + 3 * ABUF;       // [3][256*64]

    int tid = threadIdx.x;
    int lane = tid & 63;
    int wv = tid >> 6;               // 0..7
    int wm = wv & 1;                 // 2 M-halves (64 rows each)
    int wn = wv >> 1;                // 4 N-quarters (64 cols each)
    int kq = lane >> 4;              // quad 0..3
    int l15 = lane & 15;

    // staging: A = 2 x 512 slots, B = 4 x 512 slots; slot -> (m = slot>>3,
    // kc = slot&7). LDS dest LINEAR slot*16B; global col pre-swizzled.
    const u16* aS[2]; int aOff[2];
    const u16* bS[4]; int bOff[4];
#pragma unroll
    for (int i = 0; i < 2; ++i) {
        int slot = i * 512 + tid;
        int m = slot >> 3;
        int kcs = (slot & 7) ^ (m & 7);
        aS[i] = A + (size_t)(row0 + m) * lda + kcs * 8;
        aOff[i] = slot * 8;
    }
#pragma unroll
    for (int i = 0; i < 4; ++i) {
        int slot = i * 512 + tid;
        int m = slot >> 3;
        int kcs = (slot & 7) ^ (m & 7);
        bS[i] = Bt + (size_t)(n0 + m) * ldb + kcs * 8;
        bOff[i] = slot * 8;
    }

    auto stage = [&](int buf, int k0) {
#pragma unroll
        for (int i = 0; i < 2; ++i) gload16(As + buf * ABUF + aOff[i], aS[i] + k0);
#pragma unroll
        for (int i = 0; i < 4; ++i) gload16(Bs + buf * BBUF + bOff[i], bS[i] + k0);
    };

    f32x4 acc[4][4];
#pragma unroll
    for (int i = 0; i < 4; ++i)
#pragma unroll
        for (int j = 0; j < 4; ++j) acc[i][j] = f32x4{0.f, 0.f, 0.f, 0.f};

    // prologue: 2 tiles in flight (12 outstanding gload_lds per wave)
    stage(0, k_begin);
    if (nt > 1) stage(1, k_begin + 64);

    int sx = l15 & 7;                // row&7 == l15&7 (wm*64, wn*64, i*16 ≡ 0 mod 8)
    int bi = 0;                      // compute buffer = t%3
    int st = 2;                      // stage buffer   = (t+2)%3
    for (int t = 0; t < nt; ++t) {
        // wait ONLY for tile t's 6 loads; tile t+1's 6 stay in flight (T4).
        if (t < nt - 1) asm volatile("s_waitcnt vmcnt(6)" ::: "memory");
        else            asm volatile("s_waitcnt vmcnt(0)" ::: "memory");
        // RAW barrier: does NOT drain vmcnt (unlike __syncthreads).
        __builtin_amdgcn_s_barrier();
        __builtin_amdgcn_sched_barrier(0);   // rule 18: pin ds_reads below
        if (t + 2 < nt) stage(st, k_begin + (t + 2) * 64);   // freed at t-1
        const u16* Ab = As + bi * ABUF;
        const u16* Bb = Bs + bi * BBUF;
        __builtin_amdgcn_s_setprio(1);
#pragma unroll
        for (int kk = 0; kk < 2; ++kk) {
            int kc = kk * 4 + kq;
            int kca = kc ^ sx;       // swizzled column on the read side
            bf16x8 af[4], bfr[4];
#pragma unroll
            for (int i = 0; i < 4; ++i) {
                int rowA = wm * 64 + i * 16 + l15;
                af[i] = *(const bf16x8*)(Ab + rowA * 64 + kca * 8);
                int rowB = wn * 64 + i * 16 + l15;
                bfr[i] = *(const bf16x8*)(Bb + rowB * 64 + kca * 8);
            }
#pragma unroll
            for (int i = 0; i < 4; ++i)
#pragma unroll
                for (int j = 0; j < 4; ++j)
                    acc[i][j] = __builtin_amdgcn_mfma_f32_16x16x32_bf16(
                        af[i], bfr[j], acc[i][j], 0, 0, 0);
        }
        __builtin_amdgcn_s_setprio(0);
        bi = (bi == 2) ? 0 : bi + 1;
        st = (st == 2) ? 0 : st + 1;
    }

    if constexpr (MODE == 0) {
        const float* b1e = b1 + (size_t)e * F_DIM;
#pragma unroll
        for (int i = 0; i < 4; ++i) {
            int gr = row0 + wm * 64 + i * 16 + kq * 4;
#pragma unroll
            for (int j = 0; j < 4; ++j) {
                int gc = n0 + wn * 64 + j * 16 + l15;
                float bb = b1e[gc];
#pragma unroll
                for (int r = 0; r < 4; ++r) {
                    float v = acc[i][j][r] + bb;
                    Hout[(size_t)(gr + r) * F_DIM + gc] = f2b(gelu_f(v));
                }
            }
        }
    } else {
        const float* b2e = b2 + (size_t)e * D_DIM;
        bool addBias = (k_begin == 0);
#pragma unroll
        for (int i = 0; i < 4; ++i) {
            int grb = row0 + wm * 64 + i * 16 + kq * 4;
#pragma unroll
            for (int r = 0; r < 4; ++r) {
                int tok = rowmap[grb + r];
                float g = rowgate[grb + r];
                if (tok >= 0 && tok < T_TOK) {
                    float* orow = outm + (size_t)tok * D_DIM;
#pragma unroll
                    for (int j = 0; j < 4; ++j) {
                        int gc = n0 + wn * 64 + j * 16 + l15;
                        float bb = addBias ? b2e[gc] : 0.f;
                        atomicAdd(orow + gc, g * (acc[i][j][r] + bb));
                    }
                }
            }
        }
    }
}

// ---------------- workspace layout (bytes) ----------------------------------
#define OFF_CNTH    0x10000u     // int[64*8] per-block histograms
#define OFF_OFFS    0x10900u     // int[9]
#define OFF_IDX     0x20000u     // int[T*2]
#define OFF_GATE    0x28000u     // float[T*2]
#define OFF_ROWMAP  0x30000u     // int[NROWS]
#define OFF_ROWGATE 0x40000u     // float[NROWS]
#define OFF_XG      0x900000u    // 9.44 MB u16[NROWS*D]  -> ends 0x1200000
#define OFF_W1T     0x1200000u   // 16.78 MB u16[E][F][D] -> ends 0x2200000
#define OFF_W2T     0x2200000u   // 16.78 MB u16[E][D][F] -> ends 0x3200000
#define OFF_HG      0x3200000u   // 37.75 MB u16[NROWS*F] -> ends 0x5600000

extern "C" void kernel_launch(void* const* d_in, const int* in_sizes, int n_in,
                              void* d_out, int out_size, void* d_ws, size_t ws_size,
                              hipStream_t stream) {
    const float* x       = (const float*)d_in[0];
    const float* anchors = (const float*)d_in[1];
    const float* W1      = (const float*)d_in[2];
    const float* b1      = (const float*)d_in[3];
    const float* W2      = (const float*)d_in[4];
    const float* b2      = (const float*)d_in[5];
    float* out = (float*)d_out;

    char* ws = (char*)d_ws;
    int*   cnthist = (int*)(ws + OFF_CNTH);
    int*   offs    = (int*)(ws + OFF_OFFS);
    int*   idxs    = (int*)(ws + OFF_IDX);
    float* gates   = (float*)(ws + OFF_GATE);
    int*   rowmap  = (int*)(ws + OFF_ROWMAP);
    float* rowgate = (float*)(ws + OFF_ROWGATE);
    u16*   Xg      = (u16*)(ws + OFF_XG);
    u16*   W1T     = (u16*)(ws + OFF_W1T);
    u16*   W2T     = (u16*)(ws + OFF_W2T);
    u16*   Hg      = (u16*)(ws + OFF_HG);

    // d_out sections (fp32 elements): out | a_n | scores | topk_idx
    float* out_main   = out;
    float* out_an     = out + (size_t)T_TOK * D_DIM;
    float* out_scores = out_an + E_EXP * D_DIM;
    float* out_idx    = out_scores + (size_t)T_TOK * E_EXP;

    // allow 144 KB dynamic LDS (gfx950 has 160 KB/CU); once per process
    static bool attr_done = false;
    if (!attr_done) {
        hipFuncSetAttribute((const void*)gemm_k<0>,
                            hipFuncAttributeMaxDynamicSharedMemorySize, GEMM_LDS);
        hipFuncSetAttribute((const void*)gemm_k<1>,
                            hipFuncAttributeMaxDynamicSharedMemorySize, GEMM_LDS);
        attr_done = true;
    }

    pre_k<<<PRE_BLOCKS, 256, 0, stream>>>(x, anchors, W1, W1T, W2, W2T,
                                          out_main, out_an, out_scores, out_idx,
                                          idxs, gates, cnthist);
    assign_k<<<1, 1024, 0, stream>>>(cnthist, offs, idxs, gates, rowmap, rowgate);
    gather_k<<<NROWS, 256, 0, stream>>>(x, rowmap, Xg);
    // gemm1: 8 n-tiles(256) x 72 m-tiles(128) = 576 blocks (1D, XCD-swizzled)
    gemm_k<0><<<8 * MAXTILES, 512, GEMM_LDS, stream>>>(
        Xg, D_DIM, W1T, D_DIM, Hg, b1, nullptr, nullptr,
        rowmap, nullptr, offs, D_DIM, 8);
    // gemm2: 2 n-tiles(256) x 72 m-tiles x splitK2 = 288 blocks
    gemm_k<1><<<2 * MAXTILES * 2, 512, GEMM_LDS, stream>>>(
        Hg, F_DIM, W2T, F_DIM, nullptr, nullptr, out_main, b2,
        rowmap, rowgate, offs, F_DIM / 2, 2);
}

// Round 5
// 225.778 us; speedup vs baseline: 1.2414x; 1.2171x over previous
//
#include <hip/hip_runtime.h>
#include <cstdint>

// ---------------------------------------------------------------------------
// Round 18. r14-r17 arc post-mortem: gemm duration tracks resident blocks/CU
// and NOTHING else (r13 4/CU=66us, r14 2/CU=88, r15-17 1/CU=94 across three
// different pipeline schedules, counters bit-identical). ILP-pipelining at
// low occupancy returned exactly zero on this kernel. Revert gemm to r13's
// proven high-TLP core: 128x128 tile, 256 thr, 32KB static LDS,
// launch_bounds(256,4), drain-to-0 schedule. Keep r16's fused front-end
// (pre_k/assign_k/gather_k, saved ~27us of gaps). Single tracked delta vs
// r13 core: XOR col swizzle kept (proven correct; predicted timing-null at
// 2-phase per m252; removes the 6.7M-conflict confound).
// Predict: gemm1/gemm2 ~64-67us each, conflicts 0, occ ~19%, total ~215-225.
// ---------------------------------------------------------------------------

#define T_TOK 4096
#define D_DIM 512
#define F_DIM 2048
#define E_EXP 8
#define NROWS 9216      // 8192 assignments + 8*128 pad
#define MAXTILES 72     // NROWS / 128

typedef __bf16 bf16x8 __attribute__((ext_vector_type(8)));
typedef float  f32x4  __attribute__((ext_vector_type(4)));
typedef unsigned short u16;

__device__ __forceinline__ u16 f2b(float f) {
    return __builtin_bit_cast(unsigned short, (__bf16)f);
}
__device__ __forceinline__ void gload16(void* lds, const void* g) {
    __builtin_amdgcn_global_load_lds(
        (const __attribute__((address_space(1))) void*)g,
        (__attribute__((address_space(3))) void*)lds, 16, 0, 0);
}
// tanh-approx GELU (err ~3e-4 << bf16 ulp)
__device__ __forceinline__ float gelu_f(float v) {
    float z = 0.7978845608f * (v + 0.044715f * v * v * v);
    float t = 1.0f - 2.0f / (1.0f + __expf(2.0f * z));
    return 0.5f * v * (1.0f + t);
}

// ---------------- transpose tile body (shared by pre_k) ---------------------
__device__ __forceinline__ void tbody(const float* __restrict__ in,
                                      u16* __restrict__ out, int R, int C,
                                      int c0, int r0, int tid,
                                      float (*t)[65]) {
    int cq = tid & 15, rb = tid >> 4;
#pragma unroll
    for (int pass = 0; pass < 4; ++pass) {
        int rr = rb + pass * 16;
        float4 v = *(const float4*)(in + (size_t)(r0 + rr) * C + c0 + cq * 4);
        t[rr][cq * 4 + 0] = v.x; t[rr][cq * 4 + 1] = v.y;
        t[rr][cq * 4 + 2] = v.z; t[rr][cq * 4 + 3] = v.w;
    }
    __syncthreads();
    int rg = tid & 15, cb = tid >> 4;
#pragma unroll
    for (int pass = 0; pass < 4; ++pass) {
        int c = cb + pass * 16;
        ushort4 o;
        o.x = f2b(t[rg * 4 + 0][c]); o.y = f2b(t[rg * 4 + 1][c]);
        o.z = f2b(t[rg * 4 + 2][c]); o.w = f2b(t[rg * 4 + 3][c]);
        *(ushort4*)(out + (size_t)(c0 + c) * R + r0 + rg * 4) = o;
    }
}

// ---------------- pre_k: routing + W-transposes + outm zero, ONE dispatch ---
// blocks [0,64): routing (in-block anchor norm, per-block hist -> cnthist)
// blocks [64,64+4096): W1/W2 transpose
// blocks [4160,4160+1024): zero outm (4096x512 f32)
#define RT_BLKS 64
#define TR_BLKS 4096
#define ZO_BLKS 1024
#define PRE_BLOCKS (RT_BLKS + TR_BLKS + ZO_BLKS)

__global__ void pre_k(const float* __restrict__ x, const float* __restrict__ anchors,
                      const float* __restrict__ W1, u16* __restrict__ W1T,
                      const float* __restrict__ W2, u16* __restrict__ W2T,
                      float* __restrict__ outm, float* __restrict__ dout_an,
                      float* __restrict__ dout_scores, float* __restrict__ dout_idx,
                      int* __restrict__ idxs, float* __restrict__ gates,
                      int* __restrict__ cnthist) {
    __shared__ float shpool[E_EXP * 544];   // routing: anl; transpose: 64x65
    __shared__ int hist[E_EXP];
    int b = blockIdx.x;
    int tid = threadIdx.x;

    if (b >= RT_BLKS + TR_BLKS) {           // ---- zero outm ----
        int zb = b - (RT_BLKS + TR_BLKS);
        float4* o4 = (float4*)outm;
        int i = zb * 256 + tid;             // 262144 threads x 2 float4
        o4[i] = float4{0.f, 0.f, 0.f, 0.f};
        o4[i + ZO_BLKS * 256] = float4{0.f, 0.f, 0.f, 0.f};
        return;
    }
    if (b >= RT_BLKS) {                     // ---- transposes ----
        float (*tsh)[65] = (float(*)[65])shpool;   // 4160 floats <= 4352
        int tt = b - RT_BLKS;
        if (tt < 2048) {                    // W1 [E][512][2048] -> [E][2048][512]
            int bx = tt & 31, by = (tt >> 5) & 7, bz = tt >> 8;
            size_t zoff = (size_t)bz * D_DIM * F_DIM;
            tbody(W1 + zoff, W1T + zoff, D_DIM, F_DIM, bx * 64, by * 64, tid, tsh);
        } else {                            // W2 [E][2048][512] -> [E][512][2048]
            int t2 = tt - 2048;
            int bx = t2 & 7, by = (t2 >> 3) & 31, bz = t2 >> 8;
            size_t zoff = (size_t)bz * D_DIM * F_DIM;
            tbody(W2 + zoff, W2T + zoff, F_DIM, D_DIM, bx * 64, by * 64, tid, tsh);
        }
        return;
    }

    // ---- routing ----
    float* anl = shpool;                    // [e][p*136 + i], i<128
    if (tid < E_EXP) hist[tid] = 0;
    for (int i = tid; i < E_EXP * D_DIM; i += 256) {
        int e = i >> 9, d = i & 511;
        anl[e * 544 + (d >> 7) * 136 + (d & 127)] = anchors[i];
    }
    __syncthreads();
    {   // normalize anchors in LDS: 32 threads per anchor
        int e = tid >> 5, l = tid & 31;
        float ss = 0.f;
        for (int d = l; d < D_DIM; d += 32) {
            float v = anl[e * 544 + (d >> 7) * 136 + (d & 127)];
            ss += v * v;
        }
#pragma unroll
        for (int off = 16; off >= 1; off >>= 1) ss += __shfl_xor(ss, off, 32);
        float inv = 1.0f / fmaxf(sqrtf(ss), 1e-8f);
        for (int d = l; d < D_DIM; d += 32) {
            int ix = e * 544 + (d >> 7) * 136 + (d & 127);
            float nv = anl[ix] * inv;
            anl[ix] = nv;
            if (b == 0) dout_an[e * D_DIM + d] = nv;
        }
    }
    __syncthreads();

    int p = tid & 3;
    int tok = b * 64 + (tid >> 2);
    const float4* xr = (const float4*)(x + (size_t)tok * D_DIM + p * 128);
    const float* ab = &anl[p * 136];
    float dot[E_EXP] = {};
    float ss = 0.f;
    for (int c = 0; c < 32; ++c) {
        float4 xv = xr[c];
        ss += xv.x*xv.x + xv.y*xv.y + xv.z*xv.z + xv.w*xv.w;
#pragma unroll
        for (int e = 0; e < E_EXP; ++e) {
            float4 av = *(const float4*)&ab[e * 544 + c * 4];
            dot[e] += xv.x*av.x + xv.y*av.y + xv.z*av.z + xv.w*av.w;
        }
    }
#pragma unroll
    for (int off = 1; off <= 2; off <<= 1) {
        ss += __shfl_xor(ss, off, 64);
#pragma unroll
        for (int e = 0; e < E_EXP; ++e) dot[e] += __shfl_xor(dot[e], off, 64);
    }

    if (p == 0) {
        float inv = 1.0f / fmaxf(sqrtf(ss), 1e-8f);
        float s[E_EXP];
#pragma unroll
        for (int e = 0; e < E_EXP; ++e) s[e] = dot[e] * inv;
        int i0 = 0; float b0 = s[0];
#pragma unroll
        for (int e = 1; e < E_EXP; ++e) if (s[e] > b0) { b0 = s[e]; i0 = e; }
        int i1 = -1; float b1v = -1e30f;
#pragma unroll
        for (int e = 0; e < E_EXP; ++e)
            if (e != i0 && s[e] > b1v) { b1v = s[e]; i1 = e; }
        if (i1 < 0) { i1 = (i0 + 1) & 7; b1v = s[i1]; }   // NaN-safety
        float g0 = 1.0f / (1.0f + expf(b1v - b0));
        float g1 = 1.0f - g0;
#pragma unroll
        for (int e = 0; e < E_EXP; ++e) dout_scores[tok * E_EXP + e] = s[e];
        dout_idx[tok * 2 + 0] = (float)i0;
        dout_idx[tok * 2 + 1] = (float)i1;
        idxs[tok * 2 + 0] = i0; idxs[tok * 2 + 1] = i1;
        gates[tok * 2 + 0] = g0; gates[tok * 2 + 1] = g1;
        atomicAdd(&hist[i0], 1);
        atomicAdd(&hist[i1], 1);
    }
    __syncthreads();
    if (tid < E_EXP) cnthist[b * E_EXP + tid] = hist[tid];
}

// ---------------- offsets + slot assignment + pad rows, ONE block -----------
__global__ void assign_k(const int* __restrict__ cnthist, int* __restrict__ offs,
                         const int* __restrict__ idxs, const float* __restrict__ gates,
                         int* __restrict__ rowmap, float* __restrict__ rowgate) {
    __shared__ int scur[E_EXP];
    __shared__ int soff[E_EXP + 1];
    __shared__ int scnt[E_EXP];
    int tid = threadIdx.x;
    if (tid < E_EXP) {                      // sum 64 per-block histograms
        int s = 0;
        for (int b = 0; b < RT_BLKS; ++b) s += cnthist[b * E_EXP + tid];
        scnt[tid] = s;
    }
    __syncthreads();
    if (tid == 0) {
        int acc = 0;
        for (int e = 0; e < E_EXP; ++e) {
            soff[e] = acc; offs[e] = acc; scur[e] = acc;
            acc += (scnt[e] + 127) & ~127;
        }
        soff[E_EXP] = acc; offs[E_EXP] = acc;
    }
    __syncthreads();
    for (int t = tid; t < T_TOK; t += 1024) {
#pragma unroll
        for (int k = 0; k < 2; ++k) {
            int e = idxs[t * 2 + k];
            e = min(max(e, 0), E_EXP - 1);
            int r = atomicAdd(&scur[e], 1);
            if (r >= 0 && r < NROWS) {
                rowmap[r] = t;
                rowgate[r] = gates[t * 2 + k];
            }
        }
    }
    __syncthreads();
    // pad rows [offs[e]+cnt[e], offs[e+1]) -> rowmap=-1, rowgate=0
#pragma unroll
    for (int e = 0; e < E_EXP; ++e) {
        int s = soff[e] + scnt[e];
        int fin = soff[e + 1];
        for (int r = s + tid; r < fin; r += 1024) {
            rowmap[r] = -1; rowgate[r] = 0.f;
        }
    }
}

// ---------------- gather: Xg rows from x via rowmap -------------------------
__global__ void gather_k(const float* __restrict__ x, const int* __restrict__ rowmap,
                         u16* __restrict__ Xg) {
    int b = blockIdx.x;
    int tid = threadIdx.x;
    int t = rowmap[b];
    int c = tid * 2;
    ushort2 o;
    if (t < 0 || t >= T_TOK) { o.x = 0; o.y = 0; }
    else {
        float2 v = *(const float2*)(x + (size_t)t * D_DIM + c);
        o.x = f2b(v.x); o.y = f2b(v.y);
    }
    *(ushort2*)(Xg + (size_t)b * D_DIM + c) = o;
}

// ---------------- grouped GEMM core (r18 = r13 core + swizzle) --------------
// MODE 0: Hg = bf16(gelu(Xg @ W1e^T + b1e))         (N=F, K=D), NT=16
// MODE 1: out[tok] += gate*(Hg @ W2e^T + [z0]b2e)   (N=D, K=F, split-K=2), NT=4
// 128x128 tile, 256 thr (4 waves, 2m x 2n, 64x64/wave), 32KB static LDS,
// drain-to-0 per K-step (high TLP: 4 blocks/CU does the latency hiding).
// XOR col swizzle kc^(row&7): global source pre-swizzled, read side XORed.
template <int MODE>
__launch_bounds__(256, 4)
__global__ void gemm_k(const u16* __restrict__ A, int lda,
                       const u16* __restrict__ BtBase, int ldb,
                       u16* __restrict__ Hout, const float* __restrict__ b1,
                       float* __restrict__ outm, const float* __restrict__ b2,
                       const int* __restrict__ rowmap, const float* __restrict__ rowgate,
                       const int* __restrict__ offs, int kPer, int nT) {
    int L = blockIdx.x;
    int per = gridDim.x >> 3;
    int tile = (L & 7) * per + (L >> 3);
    int z = 0;
    if (MODE == 1) {                 // split-K 2: high half of tiles is z=1
        int half = gridDim.x >> 1;
        z = tile >= half; tile -= z * half;
    }
    int mtile = tile / nT;
    int n0 = (tile - mtile * nT) * 128;
    int row0 = mtile * 128;
    if (row0 >= offs[E_EXP]) return;
    int e = 0;
#pragma unroll
    for (int i = 1; i < E_EXP; ++i) if (row0 >= offs[i]) e = i;
    const u16* Bt = BtBase + (size_t)e * D_DIM * F_DIM;
    int k_begin = z * kPer;
    int k_end = k_begin + kPer;

    alignas(16) __shared__ u16 As[128 * 64];
    alignas(16) __shared__ u16 Bs[128 * 64];

    int tid = threadIdx.x;
    int lane = tid & 63;
    int wv = tid >> 6;
    int wm = wv & 1, wn = wv >> 1;
    int kq = lane >> 4;          // quad 0..3
    int l15 = lane & 15;

    // staging: slot = i*256 + tid; m = slot>>3; kc = slot&7.
    // LDS dest LINEAR slot*16B; global source column pre-swizzled kc^(m&7).
    const u16* aSrc[4]; const u16* bSrc[4];
    u16* aDst[4]; u16* bDst[4];
#pragma unroll
    for (int i = 0; i < 4; ++i) {
        int slot = i * 256 + tid;
        int m = slot >> 3;
        int kc = slot & 7;
        int kcs = kc ^ (m & 7);
        aSrc[i] = A + (size_t)(row0 + m) * lda + kcs * 8;
        bSrc[i] = Bt + (size_t)(n0 + m) * ldb + kcs * 8;
        aDst[i] = As + slot * 8;
        bDst[i] = Bs + slot * 8;
    }

    f32x4 acc[4][4];
#pragma unroll
    for (int i = 0; i < 4; ++i)
#pragma unroll
        for (int j = 0; j < 4; ++j) acc[i][j] = f32x4{0.f, 0.f, 0.f, 0.f};

    int sx = l15 & 7;            // row&7 == l15&7 (wm*64, i*16 ≡ 0 mod 8)
    for (int k0 = k_begin; k0 < k_end; k0 += 64) {
#pragma unroll
        for (int i = 0; i < 4; ++i) gload16(aDst[i], aSrc[i] + k0);
#pragma unroll
        for (int i = 0; i < 4; ++i) gload16(bDst[i], bSrc[i] + k0);
        asm volatile("s_waitcnt vmcnt(0)" ::: "memory");
        __syncthreads();
#pragma unroll
        for (int kk = 0; kk < 2; ++kk) {
            int kc = kk * 4 + kq;
            int kca = kc ^ sx;   // swizzled column on the read side
            bf16x8 af[4], bfr[4];
#pragma unroll
            for (int i = 0; i < 4; ++i) {
                int rowA = wm * 64 + i * 16 + l15;
                af[i] = *(const bf16x8*)(As + rowA * 64 + kca * 8);
                int rowB = wn * 64 + i * 16 + l15;
                bfr[i] = *(const bf16x8*)(Bs + rowB * 64 + kca * 8);
            }
#pragma unroll
            for (int i = 0; i < 4; ++i)
#pragma unroll
                for (int j = 0; j < 4; ++j)
                    acc[i][j] = __builtin_amdgcn_mfma_f32_16x16x32_bf16(
                        af[i], bfr[j], acc[i][j], 0, 0, 0);
        }
        __syncthreads();
    }

    if constexpr (MODE == 0) {
        const float* b1e = b1 + (size_t)e * F_DIM;
#pragma unroll
        for (int i = 0; i < 4; ++i) {
            int gr = row0 + wm * 64 + i * 16 + kq * 4;
#pragma unroll
            for (int j = 0; j < 4; ++j) {
                int gc = n0 + wn * 64 + j * 16 + l15;
                float bb = b1e[gc];
#pragma unroll
                for (int r = 0; r < 4; ++r) {
                    float v = acc[i][j][r] + bb;
                    Hout[(size_t)(gr + r) * F_DIM + gc] = f2b(gelu_f(v));
                }
            }
        }
    } else {
        const float* b2e = b2 + (size_t)e * D_DIM;
        bool addBias = (k_begin == 0);
#pragma unroll
        for (int i = 0; i < 4; ++i) {
            int grb = row0 + wm * 64 + i * 16 + kq * 4;
#pragma unroll
            for (int r = 0; r < 4; ++r) {
                int tok = rowmap[grb + r];
                float g = rowgate[grb + r];
                if (tok >= 0 && tok < T_TOK) {
                    float* orow = outm + (size_t)tok * D_DIM;
#pragma unroll
                    for (int j = 0; j < 4; ++j) {
                        int gc = n0 + wn * 64 + j * 16 + l15;
                        float bb = addBias ? b2e[gc] : 0.f;
                        atomicAdd(orow + gc, g * (acc[i][j][r] + bb));
                    }
                }
            }
        }
    }
}

// ---------------- workspace layout (bytes) ----------------------------------
#define OFF_CNTH    0x10000u     // int[64*8] per-block histograms
#define OFF_OFFS    0x10900u     // int[9]
#define OFF_IDX     0x20000u     // int[T*2]
#define OFF_GATE    0x28000u     // float[T*2]
#define OFF_ROWMAP  0x30000u     // int[NROWS]
#define OFF_ROWGATE 0x40000u     // float[NROWS]
#define OFF_XG      0x900000u    // 9.44 MB u16[NROWS*D]  -> ends 0x1200000
#define OFF_W1T     0x1200000u   // 16.78 MB u16[E][F][D] -> ends 0x2200000
#define OFF_W2T     0x2200000u   // 16.78 MB u16[E][D][F] -> ends 0x3200000
#define OFF_HG      0x3200000u   // 37.75 MB u16[NROWS*F] -> ends 0x5600000

extern "C" void kernel_launch(void* const* d_in, const int* in_sizes, int n_in,
                              void* d_out, int out_size, void* d_ws, size_t ws_size,
                              hipStream_t stream) {
    const float* x       = (const float*)d_in[0];
    const float* anchors = (const float*)d_in[1];
    const float* W1      = (const float*)d_in[2];
    const float* b1      = (const float*)d_in[3];
    const float* W2      = (const float*)d_in[4];
    const float* b2      = (const float*)d_in[5];
    float* out = (float*)d_out;

    char* ws = (char*)d_ws;
    int*   cnthist = (int*)(ws + OFF_CNTH);
    int*   offs    = (int*)(ws + OFF_OFFS);
    int*   idxs    = (int*)(ws + OFF_IDX);
    float* gates   = (float*)(ws + OFF_GATE);
    int*   rowmap  = (int*)(ws + OFF_ROWMAP);
    float* rowgate = (float*)(ws + OFF_ROWGATE);
    u16*   Xg      = (u16*)(ws + OFF_XG);
    u16*   W1T     = (u16*)(ws + OFF_W1T);
    u16*   W2T     = (u16*)(ws + OFF_W2T);
    u16*   Hg      = (u16*)(ws + OFF_HG);

    // d_out sections (fp32 elements): out | a_n | scores | topk_idx
    float* out_main   = out;
    float* out_an     = out + (size_t)T_TOK * D_DIM;
    float* out_scores = out_an + E_EXP * D_DIM;
    float* out_idx    = out_scores + (size_t)T_TOK * E_EXP;

    pre_k<<<PRE_BLOCKS, 256, 0, stream>>>(x, anchors, W1, W1T, W2, W2T,
                                          out_main, out_an, out_scores, out_idx,
                                          idxs, gates, cnthist);
    assign_k<<<1, 1024, 0, stream>>>(cnthist, offs, idxs, gates, rowmap, rowgate);
    gather_k<<<NROWS, 256, 0, stream>>>(x, rowmap, Xg);
    // gemm1: 16 n-tiles x 72 m-tiles = 1152 blocks (1D, XCD-swizzled)
    gemm_k<0><<<16 * MAXTILES, 256, 0, stream>>>(
        Xg, D_DIM, W1T, D_DIM, Hg, b1, nullptr, nullptr,
        rowmap, nullptr, offs, D_DIM, 16);
    // gemm2: 4 n-tiles x 72 m-tiles x splitK2 = 576 blocks (1D, XCD-swizzled)
    gemm_k<1><<<4 * MAXTILES * 2, 256, 0, stream>>>(
        Hg, F_DIM, W2T, F_DIM, nullptr, nullptr, out_main, b2,
        rowmap, rowgate, offs, F_DIM / 2, 4);
}